// Round 2
// baseline (3162.269 us; speedup 1.0000x reference)
//
#include <hip/hip_runtime.h>
#include <math.h>

#define HW 4096

typedef _Float16 half8_t __attribute__((ext_vector_type(8)));
typedef float f32x4 __attribute__((ext_vector_type(4)));

// ---------------- norms: inv[b,i] = 1/sqrt(sum_c f[b,c,i]^2 + 1e-6) ----------------
__global__ __launch_bounds__(256) void norm_partial(const float* __restrict__ f, int C,
                                                    float* __restrict__ part) {
    int i = blockIdx.x * 256 + threadIdx.x;
    int b = blockIdx.y;
    int cz = blockIdx.z;
    int chunk = C >> 3;
    const float* p = f + ((size_t)b * C + (size_t)cz * chunk) * HW + i;
    float s = 0.f;
    for (int c = 0; c < chunk; ++c) {
        float v = p[(size_t)c * HW];
        s = fmaf(v, v, s);
    }
    part[(cz * 2 + b) * HW + i] = s;
}

__global__ __launch_bounds__(256) void norm_finalize(const float* __restrict__ part,
                                                     float* __restrict__ inv) {
    int idx = blockIdx.x * 256 + threadIdx.x;
    int tensor = idx >> 13;
    int pos = idx & 8191;
    const float* pt = part + (size_t)tensor * 65536;
    float s = 0.f;
#pragma unroll
    for (int cz = 0; cz < 8; ++cz) s += pt[cz * 8192 + pos];
    inv[idx] = 1.0f / sqrtf(s + 1e-6f);
}

// ---------------- transpose + fp16 hi/lo split: f[b][c][pos] -> T[b][pos][c] ----------------
__global__ __launch_bounds__(256) void transpose_split(const float* __restrict__ f,
                                                       _Float16* __restrict__ hi,
                                                       _Float16* __restrict__ lo, int C) {
    __shared__ float tile[64][65];
    const int t = threadIdx.x;
    const int p0 = blockIdx.x * 64;
    const int c0 = blockIdx.y * 64;
    const int b = blockIdx.z;
    const float* src = f + ((size_t)b * C + c0) * HW + p0;
    {
        const int cl = t >> 4;
        const int pl = (t & 15) * 4;
#pragma unroll
        for (int it = 0; it < 4; ++it) {
            float4 v = *(const float4*)(src + (size_t)(cl + it * 16) * HW + pl);
            tile[cl + it * 16][pl + 0] = v.x;
            tile[cl + it * 16][pl + 1] = v.y;
            tile[cl + it * 16][pl + 2] = v.z;
            tile[cl + it * 16][pl + 3] = v.w;
        }
    }
    __syncthreads();
    const int pr = t >> 3;
    const int cb = (t & 7) * 8;
#pragma unroll
    for (int it = 0; it < 2; ++it) {
        const int p = pr + it * 32;
        union { _Float16 h[8]; float4 v4; } H, L;
#pragma unroll
        for (int u = 0; u < 8; ++u) {
            float v = tile[cb + u][p];
            _Float16 hh = (_Float16)v;
            H.h[u] = hh;
            L.h[u] = (_Float16)(v - (float)hh);
        }
        size_t o = ((size_t)b * HW + p0 + p) * C + c0 + cb;
        *(float4*)(hi + o) = H.v4;
        *(float4*)(lo + o) = L.v4;
    }
}

// ---------------- MFMA correlation GEMM (fp16 split, 3-mul) ----------------
// M[b,j,i] op= relu( (sum_c A[c,j]*B[c,i]) * invA[j] * invB[i] )
__global__ __launch_bounds__(256, 2) void corr_mfma(
    const _Float16* __restrict__ Ahi, const _Float16* __restrict__ Alo,
    const _Float16* __restrict__ Bhi, const _Float16* __restrict__ Blo,
    const float* __restrict__ invA, const float* __restrict__ invB,
    float* __restrict__ M, int C, int multiply) {
    __shared__ char lds[32768];  // Ahi | Alo | Bhi | Blo tiles, each 128x32 fp16 = 8KB
    const int tid = threadIdx.x;
    const int b = blockIdx.z;
    const int i0 = blockIdx.x * 128;
    const int j0 = blockIdx.y * 128;

    // staging sources: 8 x 16B per thread per K-tile; LDS slot (tile,row,qs) holds
    // global quad q = qs ^ ((row>>1)&3) (bank swizzle; read side un-swizzles)
    const _Float16* planes[4] = {Ahi, Alo, Bhi, Blo};
    const _Float16* srcs[8];
#pragma unroll
    for (int s = 0; s < 8; ++s) {
        int g = s * 256 + tid;
        int tile = g >> 9;
        int row = (g >> 2) & 127;
        int q = (g & 3) ^ ((row >> 1) & 3);
        int rbase = (tile < 2 ? j0 : i0) + row;
        srcs[s] = planes[tile] + ((size_t)b * HW + rbase) * C + q * 8;
    }

    const int lane = tid & 63;
    const int w = tid >> 6;
    const int wj = (w >> 1) * 64, wi = (w & 1) * 64;
    int offA[4], offB[4];
#pragma unroll
    for (int f = 0; f < 4; ++f) {
        int jr = wj + f * 16 + (lane & 15);
        offA[f] = jr * 64 + (((lane >> 4) ^ ((jr >> 1) & 3)) << 4);
        int ir = wi + f * 16 + (lane & 15);
        offB[f] = ir * 64 + (((lane >> 4) ^ ((ir >> 1) & 3)) << 4);
    }

    f32x4 acc[4][4] = {};

#pragma unroll 1
    for (int kt = 0; kt < C; kt += 32) {
#pragma unroll
        for (int s = 0; s < 8; ++s) {
            __builtin_amdgcn_global_load_lds(
                (const __attribute__((address_space(1))) void*)(srcs[s]),
                (__attribute__((address_space(3))) void*)(lds + (s * 256 + tid) * 16),
                16, 0, 0);
            srcs[s] += 32;
        }
        __syncthreads();
        half8_t ah[4], al[4], bh[4], bl[4];
#pragma unroll
        for (int f = 0; f < 4; ++f) {
            ah[f] = *(const half8_t*)(lds + offA[f]);
            al[f] = *(const half8_t*)(lds + 8192 + offA[f]);
            bh[f] = *(const half8_t*)(lds + 16384 + offB[f]);
            bl[f] = *(const half8_t*)(lds + 24576 + offB[f]);
        }
#pragma unroll
        for (int fy = 0; fy < 4; ++fy)
#pragma unroll
            for (int fx = 0; fx < 4; ++fx) {
                f32x4 c = acc[fy][fx];
                c = __builtin_amdgcn_mfma_f32_16x16x32_f16(ah[fy], bh[fx], c, 0, 0, 0);
                c = __builtin_amdgcn_mfma_f32_16x16x32_f16(ah[fy], bl[fx], c, 0, 0, 0);
                c = __builtin_amdgcn_mfma_f32_16x16x32_f16(al[fy], bh[fx], c, 0, 0, 0);
                acc[fy][fx] = c;
            }
        __syncthreads();
    }

    // epilogue: C/D layout col = lane&15 (i), row = (lane>>4)*4 + r (j)
    const int ib = i0 + wi + (lane & 15);
    float sB[4];
#pragma unroll
    for (int fx = 0; fx < 4; ++fx) sB[fx] = invB[b * HW + ib + fx * 16];
#pragma unroll
    for (int fy = 0; fy < 4; ++fy) {
#pragma unroll
        for (int r = 0; r < 4; ++r) {
            int j = j0 + wj + fy * 16 + ((lane >> 4) << 2) + r;
            float sA = invA[b * HW + j];
            float* mp = M + ((size_t)b * HW + j) * HW + ib;
#pragma unroll
            for (int fx = 0; fx < 4; ++fx) {
                float v = fmaxf(acc[fy][fx][r] * sA * sB[fx], 0.f);
                if (multiply) v *= mp[fx * 16];
                mp[fx * 16] = v;
            }
        }
    }
}

// ---------------- fp32 fallback GEMM (used only if ws too small) ----------------
__global__ __launch_bounds__(256) void corr_gemm(const float* __restrict__ A,
                                                 const float* __restrict__ B,
                                                 const float* __restrict__ invA,
                                                 const float* __restrict__ invB,
                                                 float* __restrict__ M,
                                                 int C, int multiply) {
    __shared__ float As[16][128];
    __shared__ float Bs[16][128];
    const int tid = threadIdx.x;
    const int b = blockIdx.z;
    const int j0 = blockIdx.y * 128;
    const int i0 = blockIdx.x * 128;
    const float* Ab = A + (size_t)b * C * HW;
    const float* Bb = B + (size_t)b * C * HW;
    const int r0 = (tid * 4) >> 7;
    const int c0 = (tid * 4) & 127;
    const float* ap = Ab + (size_t)r0 * HW + (j0 + c0);
    const float* bp = Bb + (size_t)r0 * HW + (i0 + c0);
    float acc[8][8];
#pragma unroll
    for (int r = 0; r < 8; ++r)
#pragma unroll
        for (int c = 0; c < 8; ++c) acc[r][c] = 0.f;
    float4 pa0 = *(const float4*)(ap);
    float4 pa1 = *(const float4*)(ap + (size_t)8 * HW);
    float4 pb0 = *(const float4*)(bp);
    float4 pb1 = *(const float4*)(bp + (size_t)8 * HW);
    *(float4*)&As[r0][c0] = pa0;
    *(float4*)&As[r0 + 8][c0] = pa1;
    *(float4*)&Bs[r0][c0] = pb0;
    *(float4*)&Bs[r0 + 8][c0] = pb1;
    __syncthreads();
    const int ty = tid >> 4, tx = tid & 15;
    for (int k0 = 0;;) {
        int kn = k0 + 16;
        bool have_next = (kn < C);
        if (have_next) {
            const float* an = ap + (size_t)kn * HW;
            const float* bn = bp + (size_t)kn * HW;
            pa0 = *(const float4*)(an);
            pa1 = *(const float4*)(an + (size_t)8 * HW);
            pb0 = *(const float4*)(bn);
            pb1 = *(const float4*)(bn + (size_t)8 * HW);
        }
#pragma unroll
        for (int kk = 0; kk < 16; ++kk) {
            float4 af0 = *(const float4*)&As[kk][ty * 8];
            float4 af1 = *(const float4*)&As[kk][ty * 8 + 4];
            float4 bf0 = *(const float4*)&Bs[kk][tx * 8];
            float4 bf1 = *(const float4*)&Bs[kk][tx * 8 + 4];
            float a[8]  = {af0.x, af0.y, af0.z, af0.w, af1.x, af1.y, af1.z, af1.w};
            float bb[8] = {bf0.x, bf0.y, bf0.z, bf0.w, bf1.x, bf1.y, bf1.z, bf1.w};
#pragma unroll
            for (int r = 0; r < 8; ++r)
#pragma unroll
                for (int c = 0; c < 8; ++c)
                    acc[r][c] = fmaf(a[r], bb[c], acc[r][c]);
        }
        if (!have_next) break;
        __syncthreads();
        *(float4*)&As[r0][c0] = pa0;
        *(float4*)&As[r0 + 8][c0] = pa1;
        *(float4*)&Bs[r0][c0] = pb0;
        *(float4*)&Bs[r0 + 8][c0] = pb1;
        __syncthreads();
        k0 = kn;
    }
    const int jb = j0 + ty * 8;
    const int ib = i0 + tx * 8;
    float sA[8], sB[8];
#pragma unroll
    for (int r = 0; r < 8; ++r) sA[r] = invA[b * HW + jb + r];
#pragma unroll
    for (int c = 0; c < 8; ++c) sB[c] = invB[b * HW + ib + c];
#pragma unroll
    for (int r = 0; r < 8; ++r) {
        float* mp = M + ((size_t)b * HW + (size_t)(jb + r)) * HW + ib;
        float o[8];
#pragma unroll
        for (int c = 0; c < 8; ++c) o[c] = fmaxf(acc[r][c] * sA[r] * sB[c], 0.f);
        if (multiply) {
            float4 m0 = *(const float4*)mp;
            float4 m1 = *(const float4*)(mp + 4);
            o[0] *= m0.x; o[1] *= m0.y; o[2] *= m0.z; o[3] *= m0.w;
            o[4] *= m1.x; o[5] *= m1.y; o[6] *= m1.z; o[7] *= m1.w;
        }
        float4 w0 = {o[0], o[1], o[2], o[3]};
        float4 w1 = {o[4], o[5], o[6], o[7]};
        *(float4*)mp = w0;
        *(float4*)(mp + 4) = w1;
    }
}

// ---------------- per-line soft-argmax with exact near-tie fixup ----------------
__global__ __launch_bounds__(256) void soft_argmax(
    const float* __restrict__ M, float* __restrict__ out, int colmode,
    const float* __restrict__ cf3, const float* __restrict__ lf3,
    const float* __restrict__ cf4, const float* __restrict__ lf4,
    const float* __restrict__ invc3, const float* __restrict__ invl3,
    const float* __restrict__ invc4, const float* __restrict__ invl4) {
    __shared__ float buf[HW];
    __shared__ float rv[256];
    __shared__ float rs[256];
    __shared__ int ri[256];
    __shared__ float sv2[256];
    __shared__ int si2[256];
    __shared__ float exv[2];
    const int tid = threadIdx.x;
    const int b = blockIdx.y;
    int line;
    if (colmode) {
        int bx = blockIdx.x;
        line = ((bx & 7) << 9) | (bx >> 3);
    } else {
        line = blockIdx.x;
    }
    const float* base = M + (size_t)b * HW * HW;
    if (colmode) {
        for (int j = tid; j < HW; j += 256) buf[j] = base[(size_t)j * HW + line];
    } else {
        const float* row = base + (size_t)line * HW;
        for (int j4 = tid * 4; j4 < HW; j4 += 1024)
            *(float4*)&buf[j4] = *(const float4*)&row[j4];
    }
    __syncthreads();

    // pass 1: sumsq + top-2 argmax (first-index tie-break)
    float ss = 0.f, v1 = -1.f, v2 = -1.f;
    int i1 = 0, i2 = 0;
    for (int j = tid; j < HW; j += 256) {
        float v = buf[j];
        ss = fmaf(v, v, ss);
        if (v > v1) { v2 = v1; i2 = i1; v1 = v; i1 = j; }
        else if (v > v2) { v2 = v; i2 = j; }
    }
    rv[tid] = v1; ri[tid] = i1; sv2[tid] = v2; si2[tid] = i2; rs[tid] = ss;
    __syncthreads();
    for (int s = 128; s > 0; s >>= 1) {
        if (tid < s) {
            rs[tid] += rs[tid + s];
            float b1 = rv[tid + s]; int bi1 = ri[tid + s];
            float b2 = sv2[tid + s]; int bi2 = si2[tid + s];
            float a1 = rv[tid]; int ai1 = ri[tid];
            float a2 = sv2[tid]; int ai2 = si2[tid];
            float n1, n2; int ni1, ni2;
            bool bfirst = (b1 > a1) || (b1 == a1 && bi1 < ai1);
            if (bfirst) {
                n1 = b1; ni1 = bi1;
                if (a1 > b2 || (a1 == b2 && ai1 < bi2)) { n2 = a1; ni2 = ai1; }
                else { n2 = b2; ni2 = bi2; }
            } else {
                n1 = a1; ni1 = ai1;
                if (b1 > a2 || (b1 == a2 && bi1 < ai2)) { n2 = b1; ni2 = bi1; }
                else { n2 = a2; ni2 = ai2; }
            }
            rv[tid] = n1; ri[tid] = ni1; sv2[tid] = n2; si2[tid] = ni2;
        }
        __syncthreads();
    }
    const float inv = 1.0f / sqrtf(rs[0] + 1e-6f);
    const float mv1 = rv[0];
    const float mv2 = sv2[0];
    const int mi1 = ri[0];
    const int mi2 = si2[0];
    const float vmax = mv1 * inv;
    int amax = mi1;

    // near-tie: recompute both candidates exactly in fp32 from original features
    if (mv2 >= mv1 - 1.5e-4f * mv1) {
#pragma unroll 1
        for (int cp = 0; cp < 2; ++cp) {
            int jc = cp ? mi2 : mi1;
            float d3 = 0.f, d4 = 0.f;
            for (int c = tid; c < 1024; c += 256)
                d3 = fmaf(cf3[((size_t)b * 1024 + c) * HW + jc],
                          lf3[((size_t)b * 1024 + c) * HW + line], d3);
            for (int c = tid; c < 2048; c += 256)
                d4 = fmaf(cf4[((size_t)b * 2048 + c) * HW + jc],
                          lf4[((size_t)b * 2048 + c) * HW + line], d4);
            __syncthreads();
            rs[tid] = d3; rv[tid] = d4;
            __syncthreads();
            for (int s = 128; s > 0; s >>= 1) {
                if (tid < s) { rs[tid] += rs[tid + s]; rv[tid] += rv[tid + s]; }
                __syncthreads();
            }
            if (tid == 0) {
                float e3 = fmaxf(rs[0] * invc3[b * HW + jc] * invl3[b * HW + line], 0.f);
                float e4 = fmaxf(rv[0] * invc4[b * HW + jc] * invl4[b * HW + line], 0.f);
                exv[cp] = e3 * e4;
            }
            __syncthreads();
        }
        float e1 = exv[0], e2 = exv[1];
        if (e2 > e1 || (e2 == e1 && mi2 < mi1)) amax = mi2;
    }

    const float ax = (float)(amax & 63);
    const float ay = (float)(amax >> 6);

    // pass 2: gaussian-masked softmax expectation
    float se = 0.f, sx = 0.f, sy = 0.f;
    for (int j = tid; j < HW; j += 256) {
        int x2 = j & 63, y2 = j >> 6;
        float dx = (float)x2 - ax, dy = (float)y2 - ay;
        float g = __expf(-(dx * dx + dy * dy) * 0.02f);
        float v = g * buf[j] * inv;
        float e = __expf(50.0f * (v - vmax));
        se += e;
        sx = fmaf(e, fmaf((float)x2, 2.0f / 63.0f, -1.0f), sx);
        sy = fmaf(e, fmaf((float)y2, 2.0f / 63.0f, -1.0f), sy);
    }
    __syncthreads();
    rs[tid] = se; rv[tid] = sx; buf[tid] = sy;
    __syncthreads();
    for (int s = 128; s > 0; s >>= 1) {
        if (tid < s) {
            rs[tid] += rs[tid + s];
            rv[tid] += rv[tid + s];
            buf[tid] += buf[tid + s];
        }
        __syncthreads();
    }
    if (tid == 0) {
        float gx = rv[0] / rs[0];
        float gy = buf[0] / rs[0];
        size_t gbase = colmode ? 0 : 32768;
        size_t fbase = colmode ? 16384 : 49152;
        size_t p = gbase + ((size_t)b * HW + line) * 2;
        out[p] = gx;
        out[p + 1] = gy;
        out[fbase + (size_t)(b * 2 + 0) * HW + line] = 0.f;
        out[fbase + (size_t)(b * 2 + 1) * HW + line] = 0.f;
    }
}

extern "C" void kernel_launch(void* const* d_in, const int* in_sizes, int n_in,
                              void* d_out, int out_size, void* d_ws, size_t ws_size,
                              hipStream_t stream) {
    const float* s3 = (const float*)d_in[0];
    const float* t3 = (const float*)d_in[1];
    const float* s4 = (const float*)d_in[2];
    const float* t4 = (const float*)d_in[3];
    float* out = (float*)d_out;
    float* ws = (float*)d_ws;

    // ws layout (floats): inv[32768] | part[262144] | M[2*4096*4096] | P (fp16 planes, 134MB)
    float* inv  = ws;
    float* part = ws + 32768;
    float* M    = ws + 294912;
    _Float16* Pb = (_Float16*)(ws + 33849344);
    const size_t NEED = 269615104;  // bytes

    dim3 nb(16, 2, 8);
    norm_partial<<<nb, 256, 0, stream>>>(s3, 1024, part + 0 * 65536);
    norm_partial<<<nb, 256, 0, stream>>>(t3, 1024, part + 1 * 65536);
    norm_partial<<<nb, 256, 0, stream>>>(s4, 2048, part + 2 * 65536);
    norm_partial<<<nb, 256, 0, stream>>>(t4, 2048, part + 3 * 65536);
    norm_finalize<<<128, 256, 0, stream>>>(part, inv);

    if (ws_size >= NEED) {
        const size_t pe3 = (size_t)2 * HW * 1024;   // level-3 plane elems
        const size_t pe4 = (size_t)2 * HW * 2048;
        // level 3: transpose t3, s3 -> planes; GEMM (writes M)
        dim3 t3g(64, 16, 2);
        transpose_split<<<t3g, 256, 0, stream>>>(t3, Pb + 0 * pe3, Pb + 1 * pe3, 1024);
        transpose_split<<<t3g, 256, 0, stream>>>(s3, Pb + 2 * pe3, Pb + 3 * pe3, 1024);
        dim3 gg(32, 32, 2);
        corr_mfma<<<gg, 256, 0, stream>>>(Pb + 0 * pe3, Pb + 1 * pe3, Pb + 2 * pe3, Pb + 3 * pe3,
                                          inv + 8192, inv + 0, M, 1024, 0);
        // level 4: reuse P region; GEMM multiplies into M
        dim3 t4g(64, 32, 2);
        transpose_split<<<t4g, 256, 0, stream>>>(t4, Pb + 0 * pe4, Pb + 1 * pe4, 2048);
        transpose_split<<<t4g, 256, 0, stream>>>(s4, Pb + 2 * pe4, Pb + 3 * pe4, 2048);
        corr_mfma<<<gg, 256, 0, stream>>>(Pb + 0 * pe4, Pb + 1 * pe4, Pb + 2 * pe4, Pb + 3 * pe4,
                                          inv + 24576, inv + 16384, M, 2048, 1);
    } else {
        // fp32 fallback (fits in 136 MB of ws)
        dim3 gg(32, 32, 2);
        corr_gemm<<<gg, 256, 0, stream>>>(t3, s3, inv + 8192,  inv + 0,     M, 1024, 0);
        corr_gemm<<<gg, 256, 0, stream>>>(t4, s4, inv + 24576, inv + 16384, M, 2048, 1);
    }

    dim3 rg(4096, 2);
    // s2t: lines = columns i (src), candidates = j (tgt)
    soft_argmax<<<rg, 256, 0, stream>>>(M, out, 1, t3, s3, t4, s4,
                                        inv + 8192, inv + 0, inv + 24576, inv + 16384);
    // t2s: lines = rows j (tgt), candidates = i (src)
    soft_argmax<<<rg, 256, 0, stream>>>(M, out, 0, s3, t3, s4, t4,
                                        inv + 0, inv + 8192, inv + 16384, inv + 24576);
}

// Round 3
// 1524.855 us; speedup vs baseline: 2.0738x; 2.0738x over previous
//
#include <hip/hip_runtime.h>
#include <math.h>

#define HW 4096

typedef _Float16 half8_t __attribute__((ext_vector_type(8)));
typedef float f32x4 __attribute__((ext_vector_type(4)));

// ---------------- norms: inv[b,i] = 1/sqrt(sum_c f[b,c,i]^2 + 1e-6) ----------------
__global__ __launch_bounds__(256) void norm_partial(const float* __restrict__ f, int C,
                                                    float* __restrict__ part) {
    int i = blockIdx.x * 256 + threadIdx.x;
    int b = blockIdx.y;
    int cz = blockIdx.z;
    int chunk = C >> 3;
    const float* p = f + ((size_t)b * C + (size_t)cz * chunk) * HW + i;
    float s = 0.f;
    for (int c = 0; c < chunk; ++c) {
        float v = p[(size_t)c * HW];
        s = fmaf(v, v, s);
    }
    part[(cz * 2 + b) * HW + i] = s;
}

__global__ __launch_bounds__(256) void norm_finalize(const float* __restrict__ part,
                                                     float* __restrict__ inv) {
    int idx = blockIdx.x * 256 + threadIdx.x;
    int tensor = idx >> 13;
    int pos = idx & 8191;
    const float* pt = part + (size_t)tensor * 65536;
    float s = 0.f;
#pragma unroll
    for (int cz = 0; cz < 8; ++cz) s += pt[cz * 8192 + pos];
    inv[idx] = 1.0f / sqrtf(s + 1e-6f);
}

// ------- per-batch transpose + fp16 hi/lo split: f[b][c][pos] -> T[pos][c] -------
__global__ __launch_bounds__(256) void transpose_split(const float* __restrict__ f,
                                                       _Float16* __restrict__ hi,
                                                       _Float16* __restrict__ lo,
                                                       int C, int b) {
    __shared__ float tile[64][65];
    const int t = threadIdx.x;
    const int p0 = blockIdx.x * 64;
    const int c0 = blockIdx.y * 64;
    const float* src = f + ((size_t)b * C + c0) * HW + p0;
    {
        const int cl = t >> 4;
        const int pl = (t & 15) * 4;
#pragma unroll
        for (int it = 0; it < 4; ++it) {
            float4 v = *(const float4*)(src + (size_t)(cl + it * 16) * HW + pl);
            tile[cl + it * 16][pl + 0] = v.x;
            tile[cl + it * 16][pl + 1] = v.y;
            tile[cl + it * 16][pl + 2] = v.z;
            tile[cl + it * 16][pl + 3] = v.w;
        }
    }
    __syncthreads();
    const int pr = t >> 3;
    const int cb = (t & 7) * 8;
#pragma unroll
    for (int it = 0; it < 2; ++it) {
        const int p = pr + it * 32;
        union { _Float16 h[8]; float4 v4; } H, L;
#pragma unroll
        for (int u = 0; u < 8; ++u) {
            float v = tile[cb + u][p];
            _Float16 hh = (_Float16)v;
            H.h[u] = hh;
            L.h[u] = (_Float16)(v - (float)hh);
        }
        size_t o = (size_t)(p0 + p) * C + c0 + cb;
        *(float4*)(hi + o) = H.v4;
        *(float4*)(lo + o) = L.v4;
    }
}

// ---------------- MFMA correlation GEMM (fp16 split, 3-mul), per batch ----------------
// M[b,j,i] op= relu( (sum_c A[j,c]*B[i,c]) * invA[j] * invB[i] )
__global__ __launch_bounds__(256, 2) void corr_mfma(
    const _Float16* __restrict__ Ahi, const _Float16* __restrict__ Alo,
    const _Float16* __restrict__ Bhi, const _Float16* __restrict__ Blo,
    const float* __restrict__ invA, const float* __restrict__ invB,
    float* __restrict__ M, int C, int multiply, int b) {
    __shared__ char lds[32768];  // Ahi | Alo | Bhi | Blo tiles, each 128x32 fp16 = 8KB
    const int tid = threadIdx.x;
    const int i0 = blockIdx.x * 128;
    const int j0 = blockIdx.y * 128;

    // staging: 8 x 16B per thread per K-tile; LDS slot (tile,row,qs) holds global
    // quad q = qs ^ ((row>>1)&3)  (xor bank swizzle; read side un-swizzles)
    const _Float16* planes[4] = {Ahi, Alo, Bhi, Blo};
    const _Float16* srcs[8];
#pragma unroll
    for (int s = 0; s < 8; ++s) {
        int g = s * 256 + tid;
        int tile = g >> 9;
        int row = (g >> 2) & 127;
        int q = (g & 3) ^ ((row >> 1) & 3);
        int rbase = (tile < 2 ? j0 : i0) + row;
        srcs[s] = planes[tile] + (size_t)rbase * C + q * 8;
    }

    const int lane = tid & 63;
    const int w = tid >> 6;
    const int wj = (w >> 1) * 64, wi = (w & 1) * 64;
    int offA[4], offB[4];
#pragma unroll
    for (int f = 0; f < 4; ++f) {
        int jr = wj + f * 16 + (lane & 15);
        offA[f] = jr * 64 + (((lane >> 4) ^ ((jr >> 1) & 3)) << 4);
        int ir = wi + f * 16 + (lane & 15);
        offB[f] = ir * 64 + (((lane >> 4) ^ ((ir >> 1) & 3)) << 4);
    }

    f32x4 acc[4][4] = {};

#pragma unroll 1
    for (int kt = 0; kt < C; kt += 32) {
#pragma unroll
        for (int s = 0; s < 8; ++s) {
            __builtin_amdgcn_global_load_lds(
                (const __attribute__((address_space(1))) void*)(srcs[s]),
                (__attribute__((address_space(3))) void*)(lds + (s * 256 + tid) * 16),
                16, 0, 0);
            srcs[s] += 32;
        }
        __syncthreads();
        half8_t ah[4], al[4], bh[4], bl[4];
#pragma unroll
        for (int f = 0; f < 4; ++f) {
            ah[f] = *(const half8_t*)(lds + offA[f]);
            al[f] = *(const half8_t*)(lds + 8192 + offA[f]);
            bh[f] = *(const half8_t*)(lds + 16384 + offB[f]);
            bl[f] = *(const half8_t*)(lds + 24576 + offB[f]);
        }
#pragma unroll
        for (int fy = 0; fy < 4; ++fy)
#pragma unroll
            for (int fx = 0; fx < 4; ++fx) {
                f32x4 c = acc[fy][fx];
                c = __builtin_amdgcn_mfma_f32_16x16x32_f16(ah[fy], bh[fx], c, 0, 0, 0);
                c = __builtin_amdgcn_mfma_f32_16x16x32_f16(ah[fy], bl[fx], c, 0, 0, 0);
                c = __builtin_amdgcn_mfma_f32_16x16x32_f16(al[fy], bh[fx], c, 0, 0, 0);
                acc[fy][fx] = c;
            }
        __syncthreads();
    }

    // epilogue: C/D layout col(i) = lane&15, row(j) = (lane>>4)*4 + r
    const int ib = i0 + wi + (lane & 15);
    float sB[4];
#pragma unroll
    for (int fx = 0; fx < 4; ++fx) sB[fx] = invB[b * HW + ib + fx * 16];
#pragma unroll
    for (int fy = 0; fy < 4; ++fy) {
#pragma unroll
        for (int r = 0; r < 4; ++r) {
            int j = j0 + wj + fy * 16 + ((lane >> 4) << 2) + r;
            float sA = invA[b * HW + j];
            float* mp = M + ((size_t)b * HW + j) * HW + ib;
#pragma unroll
            for (int fx = 0; fx < 4; ++fx) {
                float v = fmaxf(acc[fy][fx][r] * sA * sB[fx], 0.f);
                if (multiply) v *= mp[fx * 16];
                mp[fx * 16] = v;
            }
        }
    }
}

// ---------------- fp32 fallback GEMM (used only if ws too small) ----------------
__global__ __launch_bounds__(256) void corr_gemm(const float* __restrict__ A,
                                                 const float* __restrict__ B,
                                                 const float* __restrict__ invA,
                                                 const float* __restrict__ invB,
                                                 float* __restrict__ M,
                                                 int C, int multiply) {
    __shared__ float As[16][128];
    __shared__ float Bs[16][128];
    const int tid = threadIdx.x;
    const int b = blockIdx.z;
    const int j0 = blockIdx.y * 128;
    const int i0 = blockIdx.x * 128;
    const float* Ab = A + (size_t)b * C * HW;
    const float* Bb = B + (size_t)b * C * HW;
    const int r0 = (tid * 4) >> 7;
    const int c0 = (tid * 4) & 127;
    const float* ap = Ab + (size_t)r0 * HW + (j0 + c0);
    const float* bp = Bb + (size_t)r0 * HW + (i0 + c0);
    float acc[8][8];
#pragma unroll
    for (int r = 0; r < 8; ++r)
#pragma unroll
        for (int c = 0; c < 8; ++c) acc[r][c] = 0.f;
    float4 pa0 = *(const float4*)(ap);
    float4 pa1 = *(const float4*)(ap + (size_t)8 * HW);
    float4 pb0 = *(const float4*)(bp);
    float4 pb1 = *(const float4*)(bp + (size_t)8 * HW);
    *(float4*)&As[r0][c0] = pa0;
    *(float4*)&As[r0 + 8][c0] = pa1;
    *(float4*)&Bs[r0][c0] = pb0;
    *(float4*)&Bs[r0 + 8][c0] = pb1;
    __syncthreads();
    const int ty = tid >> 4, tx = tid & 15;
    for (int k0 = 0;;) {
        int kn = k0 + 16;
        bool have_next = (kn < C);
        if (have_next) {
            const float* an = ap + (size_t)kn * HW;
            const float* bn = bp + (size_t)kn * HW;
            pa0 = *(const float4*)(an);
            pa1 = *(const float4*)(an + (size_t)8 * HW);
            pb0 = *(const float4*)(bn);
            pb1 = *(const float4*)(bn + (size_t)8 * HW);
        }
#pragma unroll
        for (int kk = 0; kk < 16; ++kk) {
            float4 af0 = *(const float4*)&As[kk][ty * 8];
            float4 af1 = *(const float4*)&As[kk][ty * 8 + 4];
            float4 bf0 = *(const float4*)&Bs[kk][tx * 8];
            float4 bf1 = *(const float4*)&Bs[kk][tx * 8 + 4];
            float a[8]  = {af0.x, af0.y, af0.z, af0.w, af1.x, af1.y, af1.z, af1.w};
            float bb[8] = {bf0.x, bf0.y, bf0.z, bf0.w, bf1.x, bf1.y, bf1.z, bf1.w};
#pragma unroll
            for (int r = 0; r < 8; ++r)
#pragma unroll
                for (int c = 0; c < 8; ++c)
                    acc[r][c] = fmaf(a[r], bb[c], acc[r][c]);
        }
        if (!have_next) break;
        __syncthreads();
        *(float4*)&As[r0][c0] = pa0;
        *(float4*)&As[r0 + 8][c0] = pa1;
        *(float4*)&Bs[r0][c0] = pb0;
        *(float4*)&Bs[r0 + 8][c0] = pb1;
        __syncthreads();
        k0 = kn;
    }
    const int jb = j0 + ty * 8;
    const int ib = i0 + tx * 8;
    float sA[8], sB[8];
#pragma unroll
    for (int r = 0; r < 8; ++r) sA[r] = invA[b * HW + jb + r];
#pragma unroll
    for (int c = 0; c < 8; ++c) sB[c] = invB[b * HW + ib + c];
#pragma unroll
    for (int r = 0; r < 8; ++r) {
        float* mp = M + ((size_t)b * HW + (size_t)(jb + r)) * HW + ib;
        float o[8];
#pragma unroll
        for (int c = 0; c < 8; ++c) o[c] = fmaxf(acc[r][c] * sA[r] * sB[c], 0.f);
        if (multiply) {
            float4 m0 = *(const float4*)mp;
            float4 m1 = *(const float4*)(mp + 4);
            o[0] *= m0.x; o[1] *= m0.y; o[2] *= m0.z; o[3] *= m0.w;
            o[4] *= m1.x; o[5] *= m1.y; o[6] *= m1.z; o[7] *= m1.w;
        }
        float4 w0 = {o[0], o[1], o[2], o[3]};
        float4 w1 = {o[4], o[5], o[6], o[7]};
        *(float4*)mp = w0;
        *(float4*)(mp + 4) = w1;
    }
}

// ---------------- per-line soft-argmax with exact near-tie fixup ----------------
__global__ __launch_bounds__(256) void soft_argmax(
    const float* __restrict__ M, float* __restrict__ out, int colmode,
    const float* __restrict__ cf3, const float* __restrict__ lf3,
    const float* __restrict__ cf4, const float* __restrict__ lf4,
    const float* __restrict__ invc3, const float* __restrict__ invl3,
    const float* __restrict__ invc4, const float* __restrict__ invl4) {
    __shared__ float buf[HW];
    __shared__ float rv[256];
    __shared__ float rs[256];
    __shared__ int ri[256];
    __shared__ float sv2[256];
    __shared__ int si2[256];
    __shared__ float exv[2];
    const int tid = threadIdx.x;
    const int b = blockIdx.y;
    int line;
    if (colmode) {
        int bx = blockIdx.x;
        line = ((bx & 7) << 9) | (bx >> 3);
    } else {
        line = blockIdx.x;
    }
    const float* base = M + (size_t)b * HW * HW;
    if (colmode) {
        for (int j = tid; j < HW; j += 256) buf[j] = base[(size_t)j * HW + line];
    } else {
        const float* row = base + (size_t)line * HW;
        for (int j4 = tid * 4; j4 < HW; j4 += 1024)
            *(float4*)&buf[j4] = *(const float4*)&row[j4];
    }
    __syncthreads();

    // pass 1: sumsq + top-2 argmax (first-index tie-break)
    float ss = 0.f, v1 = -1.f, v2 = -1.f;
    int i1 = 0, i2 = 0;
    for (int j = tid; j < HW; j += 256) {
        float v = buf[j];
        ss = fmaf(v, v, ss);
        if (v > v1) { v2 = v1; i2 = i1; v1 = v; i1 = j; }
        else if (v > v2) { v2 = v; i2 = j; }
    }
    rv[tid] = v1; ri[tid] = i1; sv2[tid] = v2; si2[tid] = i2; rs[tid] = ss;
    __syncthreads();
    for (int s = 128; s > 0; s >>= 1) {
        if (tid < s) {
            rs[tid] += rs[tid + s];
            float b1 = rv[tid + s]; int bi1 = ri[tid + s];
            float b2 = sv2[tid + s]; int bi2 = si2[tid + s];
            float a1 = rv[tid]; int ai1 = ri[tid];
            float a2 = sv2[tid]; int ai2 = si2[tid];
            float n1, n2; int ni1, ni2;
            bool bfirst = (b1 > a1) || (b1 == a1 && bi1 < ai1);
            if (bfirst) {
                n1 = b1; ni1 = bi1;
                if (a1 > b2 || (a1 == b2 && ai1 < bi2)) { n2 = a1; ni2 = ai1; }
                else { n2 = b2; ni2 = bi2; }
            } else {
                n1 = a1; ni1 = ai1;
                if (b1 > a2 || (b1 == a2 && bi1 < ai2)) { n2 = b1; ni2 = bi1; }
                else { n2 = a2; ni2 = ai2; }
            }
            rv[tid] = n1; ri[tid] = ni1; sv2[tid] = n2; si2[tid] = ni2;
        }
        __syncthreads();
    }
    const float inv = 1.0f / sqrtf(rs[0] + 1e-6f);
    const float mv1 = rv[0];
    const float mv2 = sv2[0];
    const int mi1 = ri[0];
    const int mi2 = si2[0];
    const float vmax = mv1 * inv;
    int amax = mi1;

    // near-tie: recompute both candidates exactly in fp32 from original features
    if (mv2 >= mv1 - 1.5e-4f * mv1) {
#pragma unroll 1
        for (int cp = 0; cp < 2; ++cp) {
            int jc = cp ? mi2 : mi1;
            float d3 = 0.f, d4 = 0.f;
            for (int c = tid; c < 1024; c += 256)
                d3 = fmaf(cf3[((size_t)b * 1024 + c) * HW + jc],
                          lf3[((size_t)b * 1024 + c) * HW + line], d3);
            for (int c = tid; c < 2048; c += 256)
                d4 = fmaf(cf4[((size_t)b * 2048 + c) * HW + jc],
                          lf4[((size_t)b * 2048 + c) * HW + line], d4);
            __syncthreads();
            rs[tid] = d3; rv[tid] = d4;
            __syncthreads();
            for (int s = 128; s > 0; s >>= 1) {
                if (tid < s) { rs[tid] += rs[tid + s]; rv[tid] += rv[tid + s]; }
                __syncthreads();
            }
            if (tid == 0) {
                float e3 = fmaxf(rs[0] * invc3[b * HW + jc] * invl3[b * HW + line], 0.f);
                float e4 = fmaxf(rv[0] * invc4[b * HW + jc] * invl4[b * HW + line], 0.f);
                exv[cp] = e3 * e4;
            }
            __syncthreads();
        }
        float e1 = exv[0], e2 = exv[1];
        if (e2 > e1 || (e2 == e1 && mi2 < mi1)) amax = mi2;
    }

    const float ax = (float)(amax & 63);
    const float ay = (float)(amax >> 6);

    // pass 2: gaussian-masked softmax expectation
    float se = 0.f, sx = 0.f, sy = 0.f;
    for (int j = tid; j < HW; j += 256) {
        int x2 = j & 63, y2 = j >> 6;
        float dx = (float)x2 - ax, dy = (float)y2 - ay;
        float g = __expf(-(dx * dx + dy * dy) * 0.02f);
        float v = g * buf[j] * inv;
        float e = __expf(50.0f * (v - vmax));
        se += e;
        sx = fmaf(e, fmaf((float)x2, 2.0f / 63.0f, -1.0f), sx);
        sy = fmaf(e, fmaf((float)y2, 2.0f / 63.0f, -1.0f), sy);
    }
    __syncthreads();
    rs[tid] = se; rv[tid] = sx; buf[tid] = sy;
    __syncthreads();
    for (int s = 128; s > 0; s >>= 1) {
        if (tid < s) {
            rs[tid] += rs[tid + s];
            rv[tid] += rv[tid + s];
            buf[tid] += buf[tid + s];
        }
        __syncthreads();
    }
    if (tid == 0) {
        float gx = rv[0] / rs[0];
        float gy = buf[0] / rs[0];
        size_t gbase = colmode ? 0 : 32768;
        size_t fbase = colmode ? 16384 : 49152;
        size_t p = gbase + ((size_t)b * HW + line) * 2;
        out[p] = gx;
        out[p + 1] = gy;
        out[fbase + (size_t)(b * 2 + 0) * HW + line] = 0.f;
        out[fbase + (size_t)(b * 2 + 1) * HW + line] = 0.f;
    }
}

extern "C" void kernel_launch(void* const* d_in, const int* in_sizes, int n_in,
                              void* d_out, int out_size, void* d_ws, size_t ws_size,
                              hipStream_t stream) {
    const float* s3 = (const float*)d_in[0];
    const float* t3 = (const float*)d_in[1];
    const float* s4 = (const float*)d_in[2];
    const float* t4 = (const float*)d_in[3];
    float* out = (float*)d_out;
    float* ws = (float*)d_ws;

    // MFMA tier layout (floats):
    //   inv    [0, 32768)
    //   M      [32768, 33587200)                       134.2 MB
    //   planes [33587200 ...)  67.1 MB (per-batch, K=2048 worst case)
    //   part   overlaid at plane start (dead before transposes run)
    const size_t NEED = 201457664;  // bytes: 131072 + 134217728 + 67108864

    float* inv = ws;

    if (ws_size >= NEED) {
        float* M = ws + 32768;
        float* part = ws + 33587200;
        _Float16* P = (_Float16*)(ws + 33587200);

        dim3 nb(16, 2, 8);
        norm_partial<<<nb, 256, 0, stream>>>(s3, 1024, part + 0 * 65536);
        norm_partial<<<nb, 256, 0, stream>>>(t3, 1024, part + 1 * 65536);
        norm_partial<<<nb, 256, 0, stream>>>(s4, 2048, part + 2 * 65536);
        norm_partial<<<nb, 256, 0, stream>>>(t4, 2048, part + 3 * 65536);
        norm_finalize<<<128, 256, 0, stream>>>(part, inv);

        dim3 gg(32, 32, 1);
        // level 3 (writes M), per batch; planes: Ahi|Alo|Bhi|Blo, A = t3 (j), B = s3 (i)
        {
            const size_t pe = (size_t)HW * 1024;
            dim3 tg(64, 16, 1);
            for (int b = 0; b < 2; ++b) {
                transpose_split<<<tg, 256, 0, stream>>>(t3, P + 0 * pe, P + 1 * pe, 1024, b);
                transpose_split<<<tg, 256, 0, stream>>>(s3, P + 2 * pe, P + 3 * pe, 1024, b);
                corr_mfma<<<gg, 256, 0, stream>>>(P + 0 * pe, P + 1 * pe, P + 2 * pe, P + 3 * pe,
                                                  inv + 8192, inv + 0, M, 1024, 0, b);
            }
        }
        // level 4 (multiplies into M), per batch
        {
            const size_t pe = (size_t)HW * 2048;
            dim3 tg(64, 32, 1);
            for (int b = 0; b < 2; ++b) {
                transpose_split<<<tg, 256, 0, stream>>>(t4, P + 0 * pe, P + 1 * pe, 2048, b);
                transpose_split<<<tg, 256, 0, stream>>>(s4, P + 2 * pe, P + 3 * pe, 2048, b);
                corr_mfma<<<gg, 256, 0, stream>>>(P + 0 * pe, P + 1 * pe, P + 2 * pe, P + 3 * pe,
                                                  inv + 24576, inv + 16384, M, 2048, 1, b);
            }
        }

        dim3 rg(4096, 2);
        soft_argmax<<<rg, 256, 0, stream>>>(M, out, 1, t3, s3, t4, s4,
                                            inv + 8192, inv + 0, inv + 24576, inv + 16384);
        soft_argmax<<<rg, 256, 0, stream>>>(M, out, 0, s3, t3, s4, t4,
                                            inv + 0, inv + 8192, inv + 16384, inv + 24576);
    } else {
        // fp32 fallback (fits in ~135.4 MB of ws)
        float* part = ws + 32768;
        float* M = ws + 294912;

        dim3 nb(16, 2, 8);
        norm_partial<<<nb, 256, 0, stream>>>(s3, 1024, part + 0 * 65536);
        norm_partial<<<nb, 256, 0, stream>>>(t3, 1024, part + 1 * 65536);
        norm_partial<<<nb, 256, 0, stream>>>(s4, 2048, part + 2 * 65536);
        norm_partial<<<nb, 256, 0, stream>>>(t4, 2048, part + 3 * 65536);
        norm_finalize<<<128, 256, 0, stream>>>(part, inv);

        dim3 gg(32, 32, 2);
        corr_gemm<<<gg, 256, 0, stream>>>(t3, s3, inv + 8192,  inv + 0,     M, 1024, 0);
        corr_gemm<<<gg, 256, 0, stream>>>(t4, s4, inv + 24576, inv + 16384, M, 2048, 1);

        dim3 rg(4096, 2);
        soft_argmax<<<rg, 256, 0, stream>>>(M, out, 1, t3, s3, t4, s4,
                                            inv + 8192, inv + 0, inv + 24576, inv + 16384);
        soft_argmax<<<rg, 256, 0, stream>>>(M, out, 0, s3, t3, s4, t4,
                                            inv + 0, inv + 8192, inv + 16384, inv + 24576);
    }
}

// Round 4
// 1109.653 us; speedup vs baseline: 2.8498x; 1.3742x over previous
//
#include <hip/hip_runtime.h>
#include <math.h>

#define HW 4096
#define FIXUP_THR 4e-3f

typedef _Float16 half8_t __attribute__((ext_vector_type(8)));
typedef float f32x4 __attribute__((ext_vector_type(4)));

// ---------------- norms: inv[tensor][b][i] = 1/sqrt(sum_c f[b,c,i]^2 + 1e-6) ----------------
__global__ __launch_bounds__(256) void norm_partial(const float* __restrict__ f, int C,
                                                    float* __restrict__ part) {
    int i = blockIdx.x * 256 + threadIdx.x;
    int b = blockIdx.y;
    int cz = blockIdx.z;
    int chunk = C >> 3;
    const float* p = f + ((size_t)b * C + (size_t)cz * chunk) * HW + i;
    float s = 0.f;
    for (int c = 0; c < chunk; ++c) {
        float v = p[(size_t)c * HW];
        s = fmaf(v, v, s);
    }
    part[(cz * 2 + b) * HW + i] = s;
}

__global__ __launch_bounds__(256) void norm_finalize(const float* __restrict__ part,
                                                     float* __restrict__ inv) {
    int idx = blockIdx.x * 256 + threadIdx.x;   // 0..32767 (4 tensors x 8192)
    int tensor = idx >> 13;
    int pos = idx & 8191;
    const float* pt = part + (size_t)tensor * 65536;
    float s = 0.f;
#pragma unroll
    for (int cz = 0; cz < 8; ++cz) s += pt[cz * 8192 + pos];
    inv[idx] = 1.0f / sqrtf(s + 1e-6f);
}

// ------- per-batch transpose to fp16: f[b][c][pos] -> T[pos][c] (hi only) -------
__global__ __launch_bounds__(256) void transpose_half(const float* __restrict__ f,
                                                      _Float16* __restrict__ out,
                                                      int C, int b) {
    __shared__ float tile[64][65];
    const int t = threadIdx.x;
    const int p0 = blockIdx.x * 64;
    const int c0 = blockIdx.y * 64;
    const float* src = f + ((size_t)b * C + c0) * HW + p0;
    {
        const int cl = t >> 4;
        const int pl = (t & 15) * 4;
#pragma unroll
        for (int it = 0; it < 4; ++it) {
            float4 v = *(const float4*)(src + (size_t)(cl + it * 16) * HW + pl);
            tile[cl + it * 16][pl + 0] = v.x;
            tile[cl + it * 16][pl + 1] = v.y;
            tile[cl + it * 16][pl + 2] = v.z;
            tile[cl + it * 16][pl + 3] = v.w;
        }
    }
    __syncthreads();
    const int pr = t >> 3;
    const int cb = (t & 7) * 8;
#pragma unroll
    for (int it = 0; it < 2; ++it) {
        const int p = pr + it * 32;
        union { _Float16 h[8]; float4 v4; } H;
#pragma unroll
        for (int u = 0; u < 8; ++u) H.h[u] = (_Float16)tile[cb + u][p];
        *(float4*)(out + (size_t)(p0 + p) * C + c0 + cb) = H.v4;
    }
}

// ---------------- pure-fp16 MFMA correlation GEMM, per batch ----------------
// multiply=0: M[b,j,i] = relu(dot*invA[j]*invB[i])           (fp16 store)
// multiply=1: M *= relu(...), and writes MT[b,i,j] = M[b,j,i] (fp16)
__global__ __launch_bounds__(256, 3) void corr_mfma(
    const _Float16* __restrict__ A, const _Float16* __restrict__ B,
    const float* __restrict__ invA, const float* __restrict__ invB,
    _Float16* __restrict__ M, _Float16* __restrict__ MT,
    int C, int multiply, int b) {
    __shared__ char lds[16384];   // A tile (128x32 fp16, 8KB) | B tile (8KB)
    const int tid = threadIdx.x;
    const int i0 = blockIdx.x * 128;
    const int j0 = blockIdx.y * 128;

    // staging: 4 x 16B per thread per K-tile; LDS slot (tile,row,qs) holds global
    // quad q = qs ^ ((row>>1)&3)  (xor bank swizzle; read side un-swizzles)
    const _Float16* srcs[4];
#pragma unroll
    for (int s = 0; s < 4; ++s) {
        int g = s * 256 + tid;
        int tile = g >> 9;            // 0: A(j), 1: B(i)
        int row = (g >> 2) & 127;
        int q = (g & 3) ^ ((row >> 1) & 3);
        srcs[s] = (tile ? B + (size_t)(i0 + row) * C : A + (size_t)(j0 + row) * C) + q * 8;
    }

    const int lane = tid & 63;
    const int w = tid >> 6;
    const int wj = (w >> 1) * 64, wi = (w & 1) * 64;
    const int quad = lane >> 4;
    int offA[4], offB[4];
#pragma unroll
    for (int f = 0; f < 4; ++f) {
        int jr = wj + f * 16 + (lane & 15);
        offA[f] = jr * 64 + ((quad ^ ((jr >> 1) & 3)) << 4);
        int ir = wi + f * 16 + (lane & 15);
        offB[f] = 8192 + ir * 64 + ((quad ^ ((ir >> 1) & 3)) << 4);
    }

    f32x4 acc[4][4] = {};

#pragma unroll 1
    for (int kt = 0; kt < C; kt += 32) {
#pragma unroll
        for (int s = 0; s < 4; ++s) {
            __builtin_amdgcn_global_load_lds(
                (const __attribute__((address_space(1))) void*)(srcs[s]),
                (__attribute__((address_space(3))) void*)(lds + (s * 256 + tid) * 16),
                16, 0, 0);
            srcs[s] += 32;
        }
        __syncthreads();
        half8_t ah[4], bh[4];
#pragma unroll
        for (int f = 0; f < 4; ++f) {
            ah[f] = *(const half8_t*)(lds + offA[f]);
            bh[f] = *(const half8_t*)(lds + offB[f]);
        }
#pragma unroll
        for (int fy = 0; fy < 4; ++fy)
#pragma unroll
            for (int fx = 0; fx < 4; ++fx)
                acc[fy][fx] = __builtin_amdgcn_mfma_f32_16x16x32_f16(ah[fy], bh[fx],
                                                                     acc[fy][fx], 0, 0, 0);
        __syncthreads();
    }

    // epilogue: C/D layout col(i) = lane&15, row(j) = quad*4 + r
    const int ib = i0 + wi + (lane & 15);
    float sB[4];
#pragma unroll
    for (int fx = 0; fx < 4; ++fx) sB[fx] = invB[b * HW + ib + fx * 16];
#pragma unroll
    for (int fy = 0; fy < 4; ++fy) {
        const int jb = j0 + wj + fy * 16 + quad * 4;
        float sA[4];
#pragma unroll
        for (int r = 0; r < 4; ++r) sA[r] = invA[b * HW + jb + r];
#pragma unroll
        for (int fx = 0; fx < 4; ++fx) {
            const int ii = ib + fx * 16;
            union { _Float16 h[4]; double d; } pk;
#pragma unroll
            for (int r = 0; r < 4; ++r) {
                float v = fmaxf(acc[fy][fx][r] * sA[r] * sB[fx], 0.f);
                size_t mo = ((size_t)b * HW + (jb + r)) * HW + ii;
                if (multiply) v *= (float)M[mo];
                M[mo] = (_Float16)v;
                pk.h[r] = (_Float16)v;
            }
            if (multiply)
                *(double*)(MT + ((size_t)b * HW + ii) * HW + jb) = pk.d;
        }
    }
}

// ---------------- per-line soft-argmax with scan-based exact near-tie fixup ----------------
// colmode=1: line i (s2t), reads MT rows. colmode=0: line j (t2s), reads M rows.
__global__ __launch_bounds__(256) void soft_argmax(
    const _Float16* __restrict__ M, const _Float16* __restrict__ MT,
    float* __restrict__ out, int colmode,
    const float* __restrict__ cf3, const float* __restrict__ lf3,
    const float* __restrict__ cf4, const float* __restrict__ lf4,
    const float* __restrict__ invc3, const float* __restrict__ invl3,
    const float* __restrict__ invc4, const float* __restrict__ invl4) {
    __shared__ float buf[HW];
    __shared__ float lf[3072];
    __shared__ float rv[256];
    __shared__ float rs[256];
    __shared__ int ri[256];
    __shared__ float sv2[256];
    __shared__ int si2[256];
    __shared__ int cnd[64];
    __shared__ int ncnd;
    __shared__ float bestE;
    __shared__ int bestI;
    const int tid = threadIdx.x;
    const int b = blockIdx.y;
    const int line = blockIdx.x;

    const _Float16* src = (colmode ? MT : M) + ((size_t)b * HW + line) * HW;
    for (int j = tid; j < HW; j += 256) buf[j] = (float)src[j];
    __syncthreads();

    // pass 1: sumsq + top-2 (first-index tie-break)
    float ss = 0.f, v1 = -1.f, v2 = -1.f;
    int i1 = 0, i2 = 0;
    for (int j = tid; j < HW; j += 256) {
        float v = buf[j];
        ss = fmaf(v, v, ss);
        if (v > v1) { v2 = v1; i2 = i1; v1 = v; i1 = j; }
        else if (v > v2) { v2 = v; i2 = j; }
    }
    rv[tid] = v1; ri[tid] = i1; sv2[tid] = v2; si2[tid] = i2; rs[tid] = ss;
    __syncthreads();
    for (int s = 128; s > 0; s >>= 1) {
        if (tid < s) {
            rs[tid] += rs[tid + s];
            float b1 = rv[tid + s]; int bi1 = ri[tid + s];
            float b2 = sv2[tid + s]; int bi2 = si2[tid + s];
            float a1 = rv[tid]; int ai1 = ri[tid];
            float a2 = sv2[tid]; int ai2 = si2[tid];
            float n1, n2; int ni1, ni2;
            bool bfirst = (b1 > a1) || (b1 == a1 && bi1 < ai1);
            if (bfirst) {
                n1 = b1; ni1 = bi1;
                if (a1 > b2 || (a1 == b2 && ai1 < bi2)) { n2 = a1; ni2 = ai1; }
                else { n2 = b2; ni2 = bi2; }
            } else {
                n1 = a1; ni1 = ai1;
                if (b1 > a2 || (b1 == a2 && bi1 < ai2)) { n2 = b1; ni2 = bi1; }
                else { n2 = a2; ni2 = ai2; }
            }
            rv[tid] = n1; ri[tid] = ni1; sv2[tid] = n2; si2[tid] = ni2;
        }
        __syncthreads();
    }
    const float inv = 1.0f / sqrtf(rs[0] + 1e-6f);
    const float mv1 = rv[0];
    const float mv2 = sv2[0];
    const float vmax = mv1 * inv;
    int amax = ri[0];

    // near-tie: exactly recompute EVERY candidate within threshold of stored max
    const float cut = mv1 - FIXUP_THR * mv1;
    if (mv2 >= cut) {
        if (tid == 0) { ncnd = 0; bestE = -1.f; bestI = 1 << 30; }
        __syncthreads();
        for (int j = tid; j < HW; j += 256)
            if (buf[j] >= cut) {
                int k = atomicAdd(&ncnd, 1);
                if (k < 64) cnd[k] = j;
            }
        for (int c = tid; c < 1024; c += 256)
            lf[c] = lf3[((size_t)b * 1024 + c) * HW + line];
        for (int c = tid; c < 2048; c += 256)
            lf[1024 + c] = lf4[((size_t)b * 2048 + c) * HW + line];
        __syncthreads();
        int nc = ncnd < 64 ? ncnd : 64;
#pragma unroll 1
        for (int k = 0; k < nc; ++k) {
            int jc = cnd[k];
            float d3 = 0.f, d4 = 0.f;
            for (int c = tid; c < 1024; c += 256)
                d3 = fmaf(cf3[((size_t)b * 1024 + c) * HW + jc], lf[c], d3);
            for (int c = tid; c < 2048; c += 256)
                d4 = fmaf(cf4[((size_t)b * 2048 + c) * HW + jc], lf[1024 + c], d4);
            rs[tid] = d3; rv[tid] = d4;
            __syncthreads();
            for (int s = 128; s > 0; s >>= 1) {
                if (tid < s) { rs[tid] += rs[tid + s]; rv[tid] += rv[tid + s]; }
                __syncthreads();
            }
            if (tid == 0) {
                float e3 = fmaxf(rs[0] * invc3[b * HW + jc] * invl3[b * HW + line], 0.f);
                float e4 = fmaxf(rv[0] * invc4[b * HW + jc] * invl4[b * HW + line], 0.f);
                float e = e3 * e4;
                if (e > bestE || (e == bestE && jc < bestI)) { bestE = e; bestI = jc; }
            }
            __syncthreads();
        }
        amax = bestI;
    }

    const float ax = (float)(amax & 63);
    const float ay = (float)(amax >> 6);

    // pass 2: gaussian-masked softmax expectation (vmax >= masked max: safe shift)
    float se = 0.f, sx = 0.f, sy = 0.f;
    for (int j = tid; j < HW; j += 256) {
        int x2 = j & 63, y2 = j >> 6;
        float dx = (float)x2 - ax, dy = (float)y2 - ay;
        float g = __expf(-(dx * dx + dy * dy) * 0.02f);   // 1/(2*sigma^2)
        float v = g * buf[j] * inv;
        float e = __expf(50.0f * (v - vmax));             // beta = 50
        se += e;
        sx = fmaf(e, fmaf((float)x2, 2.0f / 63.0f, -1.0f), sx);
        sy = fmaf(e, fmaf((float)y2, 2.0f / 63.0f, -1.0f), sy);
    }
    __syncthreads();
    rs[tid] = se; rv[tid] = sx; buf[tid] = sy;
    __syncthreads();
    for (int s = 128; s > 0; s >>= 1) {
        if (tid < s) {
            rs[tid] += rs[tid + s];
            rv[tid] += rv[tid + s];
            buf[tid] += buf[tid + s];
        }
        __syncthreads();
    }
    if (tid == 0) {
        float gx = rv[0] / rs[0];
        float gy = buf[0] / rs[0];
        size_t gbase = colmode ? 0 : 32768;
        size_t fbase = colmode ? 16384 : 49152;
        size_t p = gbase + ((size_t)b * HW + line) * 2;
        out[p] = gx;
        out[p + 1] = gy;
        out[fbase + (size_t)(b * 2 + 0) * HW + line] = 0.f;
        out[fbase + (size_t)(b * 2 + 1) * HW + line] = 0.f;
    }
}

extern "C" void kernel_launch(void* const* d_in, const int* in_sizes, int n_in,
                              void* d_out, int out_size, void* d_ws, size_t ws_size,
                              hipStream_t stream) {
    const float* s3 = (const float*)d_in[0];
    const float* t3 = (const float*)d_in[1];
    const float* s4 = (const float*)d_in[2];
    const float* t4 = (const float*)d_in[3];
    float* out = (float*)d_out;
    char* base = (char*)d_ws;

    // ws layout (bytes): inv [0,131072) | M16 fp16 [131072, +67108864)
    //                    | MT16 fp16 [67239936, +67108864)
    //                    | planes / norm-part overlay [134348800, +33554432)
    // total 167,903,232 B  (< 201.4 MB proven available in round 3)
    float* inv = (float*)base;
    _Float16* M16 = (_Float16*)(base + 131072);
    _Float16* MT16 = (_Float16*)(base + 67239936);
    _Float16* P = (_Float16*)(base + 134348800);
    float* part = (float*)(base + 134348800);   // dead before transposes run

    // inv offsets: s3=0, t3=8192, s4=16384, t4=24576
    dim3 nb(16, 2, 8);
    norm_partial<<<nb, 256, 0, stream>>>(s3, 1024, part + 0 * 65536);
    norm_partial<<<nb, 256, 0, stream>>>(t3, 1024, part + 1 * 65536);
    norm_partial<<<nb, 256, 0, stream>>>(s4, 2048, part + 2 * 65536);
    norm_partial<<<nb, 256, 0, stream>>>(t4, 2048, part + 3 * 65536);
    norm_finalize<<<128, 256, 0, stream>>>(part, inv);

    dim3 gg(32, 32, 1);
    // level 3 (writes M16): A = t3 (j axis), B = s3 (i axis)
    {
        const size_t pe = (size_t)HW * 1024;
        dim3 tg(64, 16, 1);
        for (int b = 0; b < 2; ++b) {
            transpose_half<<<tg, 256, 0, stream>>>(t3, P, 1024, b);
            transpose_half<<<tg, 256, 0, stream>>>(s3, P + pe, 1024, b);
            corr_mfma<<<gg, 256, 0, stream>>>(P, P + pe, inv + 8192, inv + 0,
                                              M16, MT16, 1024, 0, b);
        }
    }
    // level 4 (multiplies into M16, emits MT16)
    {
        const size_t pe = (size_t)HW * 2048;
        dim3 tg(64, 32, 1);
        for (int b = 0; b < 2; ++b) {
            transpose_half<<<tg, 256, 0, stream>>>(t4, P, 2048, b);
            transpose_half<<<tg, 256, 0, stream>>>(s4, P + pe, 2048, b);
            corr_mfma<<<gg, 256, 0, stream>>>(P, P + pe, inv + 24576, inv + 16384,
                                              M16, MT16, 2048, 1, b);
        }
    }

    dim3 rg(4096, 2);
    // s2t: lines = src pos i (MT rows), candidates j (tgt)
    soft_argmax<<<rg, 256, 0, stream>>>(M16, MT16, out, 1, t3, s3, t4, s4,
                                        inv + 8192, inv + 0, inv + 24576, inv + 16384);
    // t2s: lines = tgt pos j (M rows), candidates i (src)
    soft_argmax<<<rg, 256, 0, stream>>>(M16, MT16, out, 0, s3, t3, s4, t4,
                                        inv + 0, inv + 8192, inv + 16384, inv + 24576);
}

// Round 5
// 744.420 us; speedup vs baseline: 4.2480x; 1.4906x over previous
//
#include <hip/hip_runtime.h>
#include <math.h>

#define HW 4096
#define FIXUP_THR 4e-3f

typedef _Float16 half8_t __attribute__((ext_vector_type(8)));
typedef _Float16 half4_t __attribute__((ext_vector_type(4)));
typedef float f32x4 __attribute__((ext_vector_type(4)));

// ------- per-batch transpose to fp16 + per-position sumsq partials -------
// f[b][c][pos] -> out[pos][c] (fp16); part[cblk][pos] = sum_{c in blk} f^2 (fp32)
__global__ __launch_bounds__(256) void transpose_half(const float* __restrict__ f,
                                                      _Float16* __restrict__ out,
                                                      float* __restrict__ part,
                                                      int C, int b) {
    __shared__ float tile[64][65];
    const int t = threadIdx.x;
    const int p0 = blockIdx.x * 64;
    const int c0 = blockIdx.y * 64;
    const float* src = f + ((size_t)b * C + c0) * HW + p0;
    {
        const int cl = t >> 4;
        const int pl = (t & 15) * 4;
#pragma unroll
        for (int it = 0; it < 4; ++it) {
            float4 v = *(const float4*)(src + (size_t)(cl + it * 16) * HW + pl);
            tile[cl + it * 16][pl + 0] = v.x;
            tile[cl + it * 16][pl + 1] = v.y;
            tile[cl + it * 16][pl + 2] = v.z;
            tile[cl + it * 16][pl + 3] = v.w;
        }
    }
    __syncthreads();
    const int pr = t >> 3;
    const int cb = (t & 7) * 8;
#pragma unroll
    for (int it = 0; it < 2; ++it) {
        const int p = pr + it * 32;
        union { _Float16 h[8]; float4 v4; } H;
        float ssq = 0.f;
#pragma unroll
        for (int u = 0; u < 8; ++u) {
            float v = tile[cb + u][p];
            H.h[u] = (_Float16)v;
            ssq = fmaf(v, v, ssq);
        }
        *(float4*)(out + (size_t)(p0 + p) * C + c0 + cb) = H.v4;
        // sum the 8 octet-partials (8 consecutive lanes share p)
        ssq += __shfl_down(ssq, 4);
        ssq += __shfl_down(ssq, 2);
        ssq += __shfl_down(ssq, 1);
        if ((t & 7) == 0) part[(size_t)blockIdx.y * 4096 + p0 + p] = ssq;
    }
}

// part order: t3 | s3 | t4 | s4 ; inv order: s3 | t3 | s4 | t4 (8192 apart, [b*4096+pos])
__global__ __launch_bounds__(256) void norm_finalize_b(const float* __restrict__ part,
                                                       float* __restrict__ inv, int b) {
    const int idx = blockIdx.x * 256 + threadIdx.x;   // 0..16383
    const int tensor = idx >> 12;
    const int pos = idx & 4095;
    const int nblk[4] = {16, 16, 32, 32};
    const int poff[4] = {0, 65536, 131072, 262144};
    const int ivoff[4] = {8192, 0, 24576, 16384};
    const float* pt = part + poff[tensor] + pos;
    float s = 0.f;
    const int n = nblk[tensor];
    for (int k = 0; k < n; ++k) s += pt[(size_t)k * 4096];
    inv[ivoff[tensor] + b * 4096 + pos] = 1.0f / sqrtf(s + 1e-6f);
}

// ---------------- fused dual-level fp16 MFMA correlation GEMM, per batch ----------------
// M[b,j,i] = relu(dot3*n3) * relu(dot4*n4)  (fp16), MT[b,i,j] = M[b,j,i]
__global__ __launch_bounds__(256, 3) void corr_fused(
    const _Float16* __restrict__ A3, const _Float16* __restrict__ B3,
    const _Float16* __restrict__ A4, const _Float16* __restrict__ B4,
    const float* __restrict__ invA3, const float* __restrict__ invB3,
    const float* __restrict__ invA4, const float* __restrict__ invB4,
    _Float16* __restrict__ M, _Float16* __restrict__ MT, int b) {
    __shared__ char lds[32768];   // A tile 128x64 fp16 (16KB) | B tile (16KB)
    const int tid = threadIdx.x;
    const int i0 = blockIdx.x * 128;
    const int j0 = blockIdx.y * 128;
    const int lane = tid & 63;
    const int w = tid >> 6;
    const int wj = (w >> 1) * 64, wi = (w & 1) * 64;
    const int quad = lane >> 4;

    // fragment LDS offsets; row stride 128 B (8 chunks of 16 B), chunk swizzle ^(row&7)
    int offA[2][4], offB[2][4];
#pragma unroll
    for (int f = 0; f < 4; ++f) {
        int jr = wj + f * 16 + (lane & 15);
        int baseA = jr * 128 + ((quad ^ (jr & 3)) << 4);
        int xkA = ((jr >> 2) & 1) << 6;
        offA[0][f] = baseA + xkA;
        offA[1][f] = baseA + (64 ^ xkA);
        int ir = wi + f * 16 + (lane & 15);
        int baseB = 16384 + ir * 128 + ((quad ^ (ir & 3)) << 4);
        int xkB = ((ir >> 2) & 1) << 6;
        offB[0][f] = baseB + xkB;
        offB[1][f] = baseB + (64 ^ xkB);
    }

    // staging slot geometry: slot g = s*256+tid; row = (g>>3)&127, chunk = g&7,
    // global chunk = chunk ^ (row&7); issues 0-3 = A tile, 4-7 = B tile
    int srow[8], selem[8];
#pragma unroll
    for (int s = 0; s < 8; ++s) {
        int g = s * 256 + tid;
        srow[s] = (g >> 3) & 127;
        selem[s] = ((g & 7) ^ (srow[s] & 7)) << 3;
    }

    half4_t v3p[4][4];
    f32x4 acc[4][4] = {};

#pragma unroll
    for (int ph = 0; ph < 2; ++ph) {
        const _Float16* Ap = ph ? A4 : A3;
        const _Float16* Bp = ph ? B4 : B3;
        const int C = ph ? 2048 : 1024;
        const _Float16* srcs[8];
#pragma unroll
        for (int s = 0; s < 8; ++s) {
            const _Float16* pl = (s < 4) ? Ap : Bp;
            int rbase = (s < 4) ? j0 : i0;
            srcs[s] = pl + (size_t)(rbase + srow[s]) * C + selem[s];
        }
#pragma unroll 1
        for (int kt = 0; kt < C; kt += 64) {
#pragma unroll
            for (int s = 0; s < 8; ++s) {
                __builtin_amdgcn_global_load_lds(
                    (const __attribute__((address_space(1))) void*)(srcs[s]),
                    (__attribute__((address_space(3))) void*)(lds + (s * 256 + tid) * 16),
                    16, 0, 0);
                srcs[s] += 64;
            }
            __syncthreads();
#pragma unroll
            for (int st = 0; st < 2; ++st) {
                half8_t a[4], bb[4];
#pragma unroll
                for (int f = 0; f < 4; ++f) {
                    a[f] = *(const half8_t*)(lds + offA[st][f]);
                    bb[f] = *(const half8_t*)(lds + offB[st][f]);
                }
#pragma unroll
                for (int fy = 0; fy < 4; ++fy)
#pragma unroll
                    for (int fx = 0; fx < 4; ++fx)
                        acc[fy][fx] = __builtin_amdgcn_mfma_f32_16x16x32_f16(
                            a[fy], bb[fx], acc[fy][fx], 0, 0, 0);
            }
            __syncthreads();
        }
        if (ph == 0) {
            // stash relu(corr3) as fp16 (same rounding as round-4's M16 store), reset acc
            const int ib = i0 + wi + (lane & 15);
            float sB[4];
#pragma unroll
            for (int fx = 0; fx < 4; ++fx) sB[fx] = invB3[b * 4096 + ib + fx * 16];
#pragma unroll
            for (int fy = 0; fy < 4; ++fy) {
                const int jb = j0 + wj + fy * 16 + quad * 4;
                float sA[4];
#pragma unroll
                for (int r = 0; r < 4; ++r) sA[r] = invA3[b * 4096 + jb + r];
#pragma unroll
                for (int fx = 0; fx < 4; ++fx)
#pragma unroll
                    for (int r = 0; r < 4; ++r) {
                        v3p[fy][fx][r] =
                            (_Float16)fmaxf(acc[fy][fx][r] * sA[r] * sB[fx], 0.f);
                        acc[fy][fx][r] = 0.f;
                    }
            }
        }
    }

    // final epilogue: level4 relu x stashed level3; C/D layout col(i)=lane&15, row(j)=quad*4+r
    const int ib = i0 + wi + (lane & 15);
    float sB[4];
#pragma unroll
    for (int fx = 0; fx < 4; ++fx) sB[fx] = invB4[b * 4096 + ib + fx * 16];
#pragma unroll
    for (int fy = 0; fy < 4; ++fy) {
        const int jb = j0 + wj + fy * 16 + quad * 4;
        float sA[4];
#pragma unroll
        for (int r = 0; r < 4; ++r) sA[r] = invA4[b * 4096 + jb + r];
#pragma unroll
        for (int fx = 0; fx < 4; ++fx) {
            const int ii = ib + fx * 16;
            union { _Float16 h[4]; double d; } pk;
#pragma unroll
            for (int r = 0; r < 4; ++r) {
                float v = fmaxf(acc[fy][fx][r] * sA[r] * sB[fx], 0.f) *
                          (float)v3p[fy][fx][r];
                M[((size_t)b * HW + (jb + r)) * HW + ii] = (_Float16)v;
                pk.h[r] = (_Float16)v;
            }
            *(double*)(MT + ((size_t)b * HW + ii) * HW + jb) = pk.d;
        }
    }
}

// ---------------- fused per-line soft-argmax (z = colmode) ----------------
__global__ __launch_bounds__(256) void soft_argmax(
    const _Float16* __restrict__ M, const _Float16* __restrict__ MT,
    float* __restrict__ out,
    const float* __restrict__ s3, const float* __restrict__ t3,
    const float* __restrict__ s4, const float* __restrict__ t4,
    const float* __restrict__ inv) {
    __shared__ float buf[HW];
    __shared__ float lf[3072];
    __shared__ float rv[256];
    __shared__ float rs[256];
    __shared__ int ri[256];
    __shared__ float sv2[256];
    __shared__ int si2[256];
    __shared__ int cnd[64];
    __shared__ int ncnd;
    __shared__ float bestE;
    __shared__ int bestI;
    const int tid = threadIdx.x;
    const int b = blockIdx.y;
    const int line = blockIdx.x;
    const int colmode = blockIdx.z;

    // role selection: colmode=1 (s2t): lines i, candidates j (tgt features)
    const float* cf3 = colmode ? t3 : s3;
    const float* lf3 = colmode ? s3 : t3;
    const float* cf4 = colmode ? t4 : s4;
    const float* lf4 = colmode ? s4 : t4;
    const float* invc3 = inv + (colmode ? 8192 : 0);
    const float* invl3 = inv + (colmode ? 0 : 8192);
    const float* invc4 = inv + (colmode ? 24576 : 16384);
    const float* invl4 = inv + (colmode ? 16384 : 24576);

    const _Float16* src = (colmode ? MT : M) + ((size_t)b * HW + line) * HW;
    const half8_t* s8 = (const half8_t*)src;
    for (int j8 = tid; j8 < 512; j8 += 256) {
        half8_t h = s8[j8];
        float* bp = buf + j8 * 8;
#pragma unroll
        for (int u = 0; u < 8; ++u) bp[u] = (float)h[u];
    }
    __syncthreads();

    // pass 1: sumsq + top-2 (first-index tie-break)
    float ss = 0.f, v1 = -1.f, v2 = -1.f;
    int i1 = 0, i2 = 0;
    for (int j = tid; j < HW; j += 256) {
        float v = buf[j];
        ss = fmaf(v, v, ss);
        if (v > v1) { v2 = v1; i2 = i1; v1 = v; i1 = j; }
        else if (v > v2) { v2 = v; i2 = j; }
    }
    rv[tid] = v1; ri[tid] = i1; sv2[tid] = v2; si2[tid] = i2; rs[tid] = ss;
    __syncthreads();
    for (int s = 128; s > 0; s >>= 1) {
        if (tid < s) {
            rs[tid] += rs[tid + s];
            float b1 = rv[tid + s]; int bi1 = ri[tid + s];
            float b2 = sv2[tid + s]; int bi2 = si2[tid + s];
            float a1 = rv[tid]; int ai1 = ri[tid];
            float a2 = sv2[tid]; int ai2 = si2[tid];
            float n1, n2; int ni1, ni2;
            bool bfirst = (b1 > a1) || (b1 == a1 && bi1 < ai1);
            if (bfirst) {
                n1 = b1; ni1 = bi1;
                if (a1 > b2 || (a1 == b2 && ai1 < bi2)) { n2 = a1; ni2 = ai1; }
                else { n2 = b2; ni2 = bi2; }
            } else {
                n1 = a1; ni1 = ai1;
                if (b1 > a2 || (b1 == a2 && bi1 < ai2)) { n2 = b1; ni2 = bi1; }
                else { n2 = a2; ni2 = ai2; }
            }
            rv[tid] = n1; ri[tid] = ni1; sv2[tid] = n2; si2[tid] = ni2;
        }
        __syncthreads();
    }
    const float inv_l = 1.0f / sqrtf(rs[0] + 1e-6f);
    const float mv1 = rv[0];
    const float mv2 = sv2[0];
    const float vmax = mv1 * inv_l;
    int amax = ri[0];

    // near-tie: exactly recompute EVERY candidate within threshold of stored max
    const float cut = mv1 - FIXUP_THR * mv1;
    if (mv2 >= cut) {
        if (tid == 0) { ncnd = 0; bestE = -1.f; bestI = 1 << 30; }
        __syncthreads();
        for (int j = tid; j < HW; j += 256)
            if (buf[j] >= cut) {
                int k = atomicAdd(&ncnd, 1);
                if (k < 64) cnd[k] = j;
            }
        for (int c = tid; c < 1024; c += 256)
            lf[c] = lf3[((size_t)b * 1024 + c) * HW + line];
        for (int c = tid; c < 2048; c += 256)
            lf[1024 + c] = lf4[((size_t)b * 2048 + c) * HW + line];
        __syncthreads();
        int nc = ncnd < 64 ? ncnd : 64;
#pragma unroll 1
        for (int k = 0; k < nc; ++k) {
            int jc = cnd[k];
            float d3 = 0.f, d4 = 0.f;
            for (int c = tid; c < 1024; c += 256)
                d3 = fmaf(cf3[((size_t)b * 1024 + c) * HW + jc], lf[c], d3);
            for (int c = tid; c < 2048; c += 256)
                d4 = fmaf(cf4[((size_t)b * 2048 + c) * HW + jc], lf[1024 + c], d4);
            rs[tid] = d3; rv[tid] = d4;
            __syncthreads();
            for (int s = 128; s > 0; s >>= 1) {
                if (tid < s) { rs[tid] += rs[tid + s]; rv[tid] += rv[tid + s]; }
                __syncthreads();
            }
            if (tid == 0) {
                float e3 = fmaxf(rs[0] * invc3[b * 4096 + jc] * invl3[b * 4096 + line], 0.f);
                float e4 = fmaxf(rv[0] * invc4[b * 4096 + jc] * invl4[b * 4096 + line], 0.f);
                float e = e3 * e4;
                if (e > bestE || (e == bestE && jc < bestI)) { bestE = e; bestI = jc; }
            }
            __syncthreads();
        }
        amax = bestI;
    }

    const float ax = (float)(amax & 63);
    const float ay = (float)(amax >> 6);

    // pass 2: gaussian-masked softmax expectation (vmax >= masked max: safe shift)
    float se = 0.f, sx = 0.f, sy = 0.f;
    for (int j = tid; j < HW; j += 256) {
        int x2 = j & 63, y2 = j >> 6;
        float dx = (float)x2 - ax, dy = (float)y2 - ay;
        float g = __expf(-(dx * dx + dy * dy) * 0.02f);   // 1/(2*sigma^2)
        float v = g * buf[j] * inv_l;
        float e = __expf(50.0f * (v - vmax));             // beta = 50
        se += e;
        sx = fmaf(e, fmaf((float)x2, 2.0f / 63.0f, -1.0f), sx);
        sy = fmaf(e, fmaf((float)y2, 2.0f / 63.0f, -1.0f), sy);
    }
    __syncthreads();
    rs[tid] = se; rv[tid] = sx; buf[tid] = sy;
    __syncthreads();
    for (int s = 128; s > 0; s >>= 1) {
        if (tid < s) {
            rs[tid] += rs[tid + s];
            rv[tid] += rv[tid + s];
            buf[tid] += buf[tid + s];
        }
        __syncthreads();
    }
    if (tid == 0) {
        float gx = rv[0] / rs[0];
        float gy = buf[0] / rs[0];
        size_t gbase = colmode ? 0 : 32768;
        size_t fbase = colmode ? 16384 : 49152;
        size_t p = gbase + ((size_t)b * HW + line) * 2;
        out[p] = gx;
        out[p + 1] = gy;
        out[fbase + (size_t)(b * 2 + 0) * HW + line] = 0.f;
        out[fbase + (size_t)(b * 2 + 1) * HW + line] = 0.f;
    }
}

extern "C" void kernel_launch(void* const* d_in, const int* in_sizes, int n_in,
                              void* d_out, int out_size, void* d_ws, size_t ws_size,
                              hipStream_t stream) {
    const float* s3 = (const float*)d_in[0];
    const float* t3 = (const float*)d_in[1];
    const float* s4 = (const float*)d_in[2];
    const float* t4 = (const float*)d_in[3];
    float* out = (float*)d_out;
    char* base = (char*)d_ws;

    // ws layout (bytes):
    //   inv    [0, 131072)                    4 tensors x [b][4096] fp32
    //   part   [131072, 1703936)              norm partials (t3|s3|t4|s4)
    //   M16    [1703936, 68812800)            fp16 2x4096x4096
    //   MT16   [68812800, 135921664)          fp16 transpose
    //   planes [135921664, 186253312)         per-batch fp16: t3|s3|t4|s4
    // total 186.3 MB (< 201.4 MB proven available)
    float* inv = (float*)base;
    float* part = (float*)(base + 131072);
    _Float16* M16 = (_Float16*)(base + 1703936);
    _Float16* MT16 = (_Float16*)(base + 68812800);
    _Float16* P = (_Float16*)(base + 135921664);
    _Float16* P3t = P;
    _Float16* P3s = P + 4194304;
    _Float16* P4t = P + 8388608;
    _Float16* P4s = P + 16777216;

    dim3 t3g(64, 16), t4g(64, 32), gg(32, 32);
    for (int b = 0; b < 2; ++b) {
        transpose_half<<<t3g, 256, 0, stream>>>(t3, P3t, part + 0, 1024, b);
        transpose_half<<<t3g, 256, 0, stream>>>(s3, P3s, part + 65536, 1024, b);
        transpose_half<<<t4g, 256, 0, stream>>>(t4, P4t, part + 131072, 2048, b);
        transpose_half<<<t4g, 256, 0, stream>>>(s4, P4s, part + 262144, 2048, b);
        norm_finalize_b<<<64, 256, 0, stream>>>(part, inv, b);
        corr_fused<<<gg, 256, 0, stream>>>(P3t, P3s, P4t, P4s,
                                           inv + 8192, inv + 0, inv + 24576, inv + 16384,
                                           M16, MT16, b);
    }

    dim3 rg(4096, 2, 2);
    soft_argmax<<<rg, 256, 0, stream>>>(M16, MT16, out, s3, t3, s4, t4, inv);
}